// Round 1
// baseline (532.358 us; speedup 1.0000x reference)
//
#include <hip/hip_runtime.h>
#include <hip/hip_bf16.h>
#include <math.h>

// Problem constants
#define C_DIM 256
#define BD    128   // B*D = 8*16
#define HW    784   // H*W = 28*28
#define CN    128
#define K_DIM 784   // SS

#define LDT   132   // padded [k][m] tile stride (132 mod 32 = 4; 16B-aligned rows)

// ---------------------------------------------------------------------------
// Kernel 1: LayerNorm over C + transpose [BD][HW][C] -> x_re [C][BD][HW]
// block: 256 threads; grid: (14 hw-tiles, 128 bd)
// ---------------------------------------------------------------------------
__global__ __launch_bounds__(256) void ln_transpose_kernel(
    const float* __restrict__ x, const float* __restrict__ lnw,
    const float* __restrict__ lnb, float* __restrict__ xre) {
  const int HT = 56;   // hw rows per block
  const int LD = 257;  // LDS row stride (conflict-free both ways)
  __shared__ float tile[HT * LD];
  __shared__ float sW[256];
  __shared__ float sB[256];
  int t = threadIdx.x;
  int bd = blockIdx.y;
  int hw0 = blockIdx.x * HT;
  sW[t] = lnw[t];
  sB[t] = lnb[t];
  const float* xb = x + ((size_t)bd * HW + hw0) * 256;
  // load: thread t handles channel c=t for each hw row (coalesced, LDS stride-1)
  for (int r = 0; r < HT; ++r) {
    tile[r * LD + t] = xb[r * 256 + t];
  }
  __syncthreads();
  int w = t >> 6, lane = t & 63;
  // each wave handles rows r = w, w+4, ...
  for (int r = w; r < HT; r += 4) {
    float v[4];
    float s = 0.f;
    for (int j = 0; j < 4; ++j) { v[j] = tile[r * LD + lane + j * 64]; s += v[j]; }
    for (int off = 32; off >= 1; off >>= 1) s += __shfl_xor(s, off, 64);
    float mu = s * (1.0f / 256.0f);
    float s2 = 0.f;
    for (int j = 0; j < 4; ++j) { float dv = v[j] - mu; s2 += dv * dv; }
    for (int off = 32; off >= 1; off >>= 1) s2 += __shfl_xor(s2, off, 64);
    float scale = rsqrtf(s2 * (1.0f / 256.0f) + 1e-5f);
    for (int j = 0; j < 4; ++j) {
      int c = lane + j * 64;
      tile[r * LD + c] = (v[j] - mu) * scale * sW[c] + sB[c];
    }
  }
  __syncthreads();
  // transposed write: wave w covers channels c = i*4 + w, lanes cover hw
  if (lane < HT) {
    for (int i = 0; i < 64; ++i) {
      int c = i * 4 + w;
      xre[(size_t)c * (BD * HW) + (size_t)bd * HW + hw0 + lane] = tile[lane * LD + c];
    }
  }
}

// ---------------------------------------------------------------------------
// Kernel 2: per-c 128x128 fp32 GEMM-dist: D = sqrt(|a|^2+|b|^2-2ab),
// writes x_distance [m][c][n] and softmax(-32 D) over n.
// block: 256 threads (16x16, 8x8 microtile); grid: 256 (one per c)
// ---------------------------------------------------------------------------
__global__ __launch_bounds__(256) void gemm_dist_kernel(
    const float* __restrict__ xre, const float* __restrict__ cc,
    float* __restrict__ out_d, float* __restrict__ out_s) {
  __shared__ float At[32 * LDT];
  __shared__ float Bt[32 * LDT];
  __shared__ float anp[2][128];
  __shared__ float bnp[2][128];
  int c = blockIdx.x;
  int t = threadIdx.x;
  int tx = t & 15, ty = t >> 4;
  const float* Ag = xre + (size_t)c * (BD * HW);
  const float* Bg = cc + (size_t)c * (CN * HW);
  float acc[8][8];
  for (int i = 0; i < 8; ++i)
    for (int j = 0; j < 8; ++j) acc[i][j] = 0.f;
  float an = 0.f, bn = 0.f;
  int nm = t >> 1;          // norm row 0..127
  int np = (t & 1) * 16;    // norm k-half
  int kk = (t & 7) * 4;     // load k offset within tile
  int mr = t >> 3;          // load row 0..31
  for (int k0 = 0; k0 < K_DIM; k0 += 32) {
    bool valid = (k0 + kk) < K_DIM;  // K=784 -> last tile half-filled, chunk-aligned
    for (int p = 0; p < 4; ++p) {
      int m = mr + p * 32;
      float4 av = valid ? *(const float4*)(Ag + (size_t)m * K_DIM + k0 + kk)
                        : make_float4(0.f, 0.f, 0.f, 0.f);
      float4 bv = valid ? *(const float4*)(Bg + (size_t)m * K_DIM + k0 + kk)
                        : make_float4(0.f, 0.f, 0.f, 0.f);
      At[(kk + 0) * LDT + m] = av.x; At[(kk + 1) * LDT + m] = av.y;
      At[(kk + 2) * LDT + m] = av.z; At[(kk + 3) * LDT + m] = av.w;
      Bt[(kk + 0) * LDT + m] = bv.x; Bt[(kk + 1) * LDT + m] = bv.y;
      Bt[(kk + 2) * LDT + m] = bv.z; Bt[(kk + 3) * LDT + m] = bv.w;
    }
    __syncthreads();
    // fold row-norm accumulation in (2 threads per row, 16 k each)
    for (int q = 0; q < 16; ++q) {
      float va = At[(np + q) * LDT + nm]; an = fmaf(va, va, an);
      float vb = Bt[(np + q) * LDT + nm]; bn = fmaf(vb, vb, bn);
    }
    for (int k = 0; k < 32; ++k) {
      float a[8], b[8];
      *(float4*)(a)     = *(const float4*)&At[k * LDT + ty * 8];
      *(float4*)(a + 4) = *(const float4*)&At[k * LDT + ty * 8 + 4];
      *(float4*)(b)     = *(const float4*)&Bt[k * LDT + tx * 8];
      *(float4*)(b + 4) = *(const float4*)&Bt[k * LDT + tx * 8 + 4];
      for (int i = 0; i < 8; ++i)
        for (int j = 0; j < 8; ++j)
          acc[i][j] = fmaf(a[i], b[j], acc[i][j]);
    }
    __syncthreads();
  }
  anp[t & 1][nm] = an;
  bnp[t & 1][nm] = bn;
  __syncthreads();
  float amn[8], bnn[8];
  for (int i = 0; i < 8; ++i) amn[i] = anp[0][ty * 8 + i] + anp[1][ty * 8 + i];
  for (int j = 0; j < 8; ++j) bnn[j] = bnp[0][tx * 8 + j] + bnp[1][tx * 8 + j];
  for (int i = 0; i < 8; ++i) {
    int m = ty * 8 + i;
    float dr[8];
    for (int j = 0; j < 8; ++j) {
      float d2 = amn[i] + bnn[j] - 2.f * acc[i][j];
      dr[j] = sqrtf(fmaxf(d2, 1e-12f));
    }
    size_t ob = ((size_t)m * 256 + c) * 128 + tx * 8;
    *(float4*)(out_d + ob)     = make_float4(dr[0], dr[1], dr[2], dr[3]);
    *(float4*)(out_d + ob + 4) = make_float4(dr[4], dr[5], dr[6], dr[7]);
    // softmax(-32*d) over the row (16 lanes with same ty hold the 128 cols)
    float mn = dr[0];
    for (int j = 1; j < 8; ++j) mn = fminf(mn, dr[j]);
    for (int off = 1; off < 16; off <<= 1) mn = fminf(mn, __shfl_xor(mn, off, 64));
    float e[8];
    float s = 0.f;
    for (int j = 0; j < 8; ++j) { e[j] = __expf(-32.f * (dr[j] - mn)); s += e[j]; }
    for (int off = 1; off < 16; off <<= 1) s += __shfl_xor(s, off, 64);
    float inv = 1.f / s;
    *(float4*)(out_s + ob)     = make_float4(e[0] * inv, e[1] * inv, e[2] * inv, e[3] * inv);
    *(float4*)(out_s + ob + 4) = make_float4(e[4] * inv, e[5] * inv, e[6] * inv, e[7] * inv);
  }
}

// ---------------------------------------------------------------------------
// Kernel 3: per-c 128x128 cluster self-distance. A = B = cc[c].
// ---------------------------------------------------------------------------
__global__ __launch_bounds__(256) void gemm_cdist_kernel(
    const float* __restrict__ cc, float* __restrict__ out_c) {
  __shared__ float Ct[32 * LDT];
  __shared__ float cnp[2][128];
  int c = blockIdx.x;
  int t = threadIdx.x;
  int tx = t & 15, ty = t >> 4;
  const float* Bg = cc + (size_t)c * (CN * HW);
  float acc[8][8];
  for (int i = 0; i < 8; ++i)
    for (int j = 0; j < 8; ++j) acc[i][j] = 0.f;
  float cn = 0.f;
  int nm = t >> 1;
  int np = (t & 1) * 16;
  int kk = (t & 7) * 4;
  int mr = t >> 3;
  for (int k0 = 0; k0 < K_DIM; k0 += 32) {
    bool valid = (k0 + kk) < K_DIM;
    for (int p = 0; p < 4; ++p) {
      int m = mr + p * 32;
      float4 bv = valid ? *(const float4*)(Bg + (size_t)m * K_DIM + k0 + kk)
                        : make_float4(0.f, 0.f, 0.f, 0.f);
      Ct[(kk + 0) * LDT + m] = bv.x; Ct[(kk + 1) * LDT + m] = bv.y;
      Ct[(kk + 2) * LDT + m] = bv.z; Ct[(kk + 3) * LDT + m] = bv.w;
    }
    __syncthreads();
    for (int q = 0; q < 16; ++q) {
      float v = Ct[(np + q) * LDT + nm]; cn = fmaf(v, v, cn);
    }
    for (int k = 0; k < 32; ++k) {
      float a[8], b[8];
      *(float4*)(a)     = *(const float4*)&Ct[k * LDT + ty * 8];
      *(float4*)(a + 4) = *(const float4*)&Ct[k * LDT + ty * 8 + 4];
      *(float4*)(b)     = *(const float4*)&Ct[k * LDT + tx * 8];
      *(float4*)(b + 4) = *(const float4*)&Ct[k * LDT + tx * 8 + 4];
      for (int i = 0; i < 8; ++i)
        for (int j = 0; j < 8; ++j)
          acc[i][j] = fmaf(a[i], b[j], acc[i][j]);
    }
    __syncthreads();
  }
  cnp[t & 1][nm] = cn;
  __syncthreads();
  float amn[8], bnn[8];
  for (int i = 0; i < 8; ++i) amn[i] = cnp[0][ty * 8 + i] + cnp[1][ty * 8 + i];
  for (int j = 0; j < 8; ++j) bnn[j] = cnp[0][tx * 8 + j] + cnp[1][tx * 8 + j];
  for (int i = 0; i < 8; ++i) {
    int m = ty * 8 + i;
    float dr[8];
    for (int j = 0; j < 8; ++j) {
      float d2 = amn[i] + bnn[j] - 2.f * acc[i][j];
      dr[j] = sqrtf(fmaxf(d2, 1e-12f));
    }
    size_t ob = (size_t)c * (128 * 128) + (size_t)m * 128 + tx * 8;
    *(float4*)(out_c + ob)     = make_float4(dr[0], dr[1], dr[2], dr[3]);
    *(float4*)(out_c + ob + 4) = make_float4(dr[4], dr[5], dr[6], dr[7]);
  }
}

extern "C" void kernel_launch(void* const* d_in, const int* in_sizes, int n_in,
                              void* d_out, int out_size, void* d_ws, size_t ws_size,
                              hipStream_t stream) {
  const float* x   = (const float*)d_in[0];
  const float* lnw = (const float*)d_in[1];
  const float* lnb = (const float*)d_in[2];
  const float* cc  = (const float*)d_in[3];
  float* out   = (float*)d_out;
  float* out_d = out;                 // x_distance       [8,16,256,128]
  float* out_s = out + 4194304;       // x_distance_assign[8,16,256,128]
  float* out_c = out + 8388608;       // cluster_dist     [256,128,128]
  float* xre   = (float*)d_ws;        // [256][128][784] fp32 = 98 MB

  ln_transpose_kernel<<<dim3(14, 128), 256, 0, stream>>>(x, lnw, lnb, xre);
  gemm_dist_kernel<<<256, 256, 0, stream>>>(xre, cc, out_d, out_s);
  gemm_cdist_kernel<<<256, 256, 0, stream>>>(cc, out_c);
}

// Round 2
// 321.921 us; speedup vs baseline: 1.6537x; 1.6537x over previous
//
#include <hip/hip_runtime.h>
#include <hip/hip_bf16.h>
#include <math.h>

// Problem constants
#define C_DIM 256
#define BD    128   // B*D
#define HW    784   // H*W = K
#define CN    128
#define KPAD  800   // K padded to 25 tiles of 32 (pad = zeros)

typedef short bf16x8 __attribute__((ext_vector_type(8)));
typedef float f32x4 __attribute__((ext_vector_type(4)));

// fp32 -> bf16 RNE
__device__ inline ushort f2b(float f) {
  unsigned u = __float_as_uint(f);
  unsigned r = (u + 0x7FFFu + ((u >> 16) & 1u)) >> 16;
  return (ushort)r;
}

// ---------------------------------------------------------------------------
// K1: LayerNorm over C + transpose -> bf16 x_re [C][BD][KPAD] + row norms
// grid (14, 128), block 256
// ---------------------------------------------------------------------------
__global__ __launch_bounds__(256) void ln_transpose_kernel(
    const float* __restrict__ x, const float* __restrict__ lnw,
    const float* __restrict__ lnb, ushort* __restrict__ xre,
    float* __restrict__ anorm) {
  const int HT = 56, LD = 257;
  __shared__ float tile[HT * LD];
  __shared__ float sW[256], sB[256];
  __shared__ float nbuf[4][256];
  int t = threadIdx.x, bd = blockIdx.y, hw0 = blockIdx.x * HT;
  sW[t] = lnw[t]; sB[t] = lnb[t];
  const float* xb = x + ((size_t)bd * HW + hw0) * 256;
  for (int r = 0; r < HT; ++r) tile[r * LD + t] = xb[r * 256 + t];
  __syncthreads();
  int w = t >> 6, lane = t & 63;
  float nrm[4] = {0.f, 0.f, 0.f, 0.f};
  for (int r = w; r < HT; r += 4) {
    float v[4]; float s = 0.f;
    for (int j = 0; j < 4; ++j) { v[j] = tile[r * LD + lane + j * 64]; s += v[j]; }
    for (int off = 32; off >= 1; off >>= 1) s += __shfl_xor(s, off, 64);
    float mu = s * (1.0f / 256.0f);
    float s2 = 0.f;
    for (int j = 0; j < 4; ++j) { float dv = v[j] - mu; s2 += dv * dv; }
    for (int off = 32; off >= 1; off >>= 1) s2 += __shfl_xor(s2, off, 64);
    float scale = rsqrtf(s2 * (1.0f / 256.0f) + 1e-5f);
    for (int j = 0; j < 4; ++j) {
      int c = lane + j * 64;
      float y = (v[j] - mu) * scale * sW[c] + sB[c];
      tile[r * LD + c] = y;
      nrm[j] = fmaf(y, y, nrm[j]);
    }
  }
  for (int j = 0; j < 4; ++j) nbuf[w][lane + j * 64] = nrm[j];
  __syncthreads();
  if (lane < HT) {
    for (int i = 0; i < 64; ++i) {
      int c = i * 4 + w;
      xre[(size_t)c * (BD * KPAD) + (size_t)bd * KPAD + hw0 + lane] =
          f2b(tile[lane * LD + c]);
    }
  } else if (blockIdx.x == 13) {
    int p = lane - 56;  // 0..7, two bf16 each -> k = 784..799 zero pad
    for (int i = 0; i < 64; ++i) {
      int c = i * 4 + w;
      *(ushort2*)(xre + (size_t)c * (BD * KPAD) + (size_t)bd * KPAD + 784 + p * 2) =
          make_ushort2(0, 0);
    }
  }
  float tot = nbuf[0][t] + nbuf[1][t] + nbuf[2][t] + nbuf[3][t];
  atomicAdd(&anorm[t * 128 + bd], tot);  // anorm[c][bd]
}

// ---------------------------------------------------------------------------
// K2: cc fp32 -> bf16 [C][CN][KPAD] + fp32 row norms + zero K-pad
// grid 1024, block 256; block b: c=b>>2, rows (b&3)*32 + wave*8 .. +8
// ---------------------------------------------------------------------------
__global__ __launch_bounds__(256) void cc_convert_kernel(
    const float* __restrict__ cc, ushort* __restrict__ ccb,
    float* __restrict__ bnorm) {
  int b = blockIdx.x, c = b >> 2;
  int t = threadIdx.x, w = t >> 6, lane = t & 63;
  int r0 = (b & 3) * 32 + w * 8;
  for (int it = 0; it < 8; ++it) {
    int r = r0 + it;
    const float4* src = (const float4*)(cc + ((size_t)c * CN + r) * HW);
    ushort* dst = ccb + (size_t)c * (CN * KPAD) + (size_t)r * KPAD;
    float nrm = 0.f;
    for (int f = lane; f < 196; f += 64) {
      float4 v = src[f];
      nrm = fmaf(v.x, v.x, nrm); nrm = fmaf(v.y, v.y, nrm);
      nrm = fmaf(v.z, v.z, nrm); nrm = fmaf(v.w, v.w, nrm);
      ushort4 o; o.x = f2b(v.x); o.y = f2b(v.y); o.z = f2b(v.z); o.w = f2b(v.w);
      *(ushort4*)(dst + f * 4) = o;
    }
    for (int off = 32; off >= 1; off >>= 1) nrm += __shfl_xor(nrm, off, 64);
    if (lane == 0) bnorm[c * 128 + r] = nrm;
    if (lane < 4) *(ushort4*)(dst + 784 + lane * 4) = make_ushort4(0, 0, 0, 0);
  }
}

// ---------------------------------------------------------------------------
// K3: MFMA GEMM-dist. grid (256, 2): y=0 -> x_re vs cc (dist + softmax),
// y=1 -> cc vs cc (cluster_dist). 128x128 tile, BK=32, 16x16x32 bf16 MFMA.
// LDS tiles staged via global_load_lds (16B/lane) with XOR chunk swizzle:
// chunk(row, q) stored at ci = row*4 + (q ^ (row&3)).
// ---------------------------------------------------------------------------
__global__ __launch_bounds__(256, 2) void gemm_mfma_kernel(
    const ushort* __restrict__ xre, const ushort* __restrict__ ccb,
    const float* __restrict__ anorm, const float* __restrict__ bnorm,
    float* __restrict__ out_d, float* __restrict__ out_s,
    float* __restrict__ out_c) {
  __shared__ __align__(16) ushort At[512 * 8];  // 128 rows x 32 bf16
  __shared__ __align__(16) ushort Bt[512 * 8];
  __shared__ float smin[2][128];
  __shared__ float ssum[2][128];
  const int c = blockIdx.x, mode = blockIdx.y;
  const int t = threadIdx.x, w = t >> 6, lane = t & 63;
  const int quad = lane >> 4, ln = lane & 15;
  const int wrow = (w >> 1) * 64, wcol = (w & 1) * 64;
  const ushort* Ag = (mode ? ccb : xre) + (size_t)c * (128 * KPAD);
  const ushort* Bg = ccb + (size_t)c * (128 * KPAD);

  f32x4 acc[4][4];
  for (int i = 0; i < 4; ++i)
    for (int j = 0; j < 4; ++j) acc[i][j] = f32x4{0.f, 0.f, 0.f, 0.f};

  // staging addressing: instruction s covers chunks ci = 128w+64s+lane
  const int ci0 = 128 * w;
  const int row0 = (ci0 + lane) >> 2;
  const int row1 = (ci0 + 64 + lane) >> 2;
  const int q0 = (lane & 3) ^ (row0 & 3);
  const int q1 = (lane & 3) ^ (row1 & 3);
  const ushort* ga0 = Ag + (size_t)row0 * KPAD + q0 * 8;
  const ushort* ga1 = Ag + (size_t)row1 * KPAD + q1 * 8;
  const ushort* gb0 = Bg + (size_t)row0 * KPAD + q0 * 8;
  const ushort* gb1 = Bg + (size_t)row1 * KPAD + q1 * 8;
  ushort* la0 = &At[ci0 * 8];
  ushort* la1 = &At[(ci0 + 64) * 8];
  ushort* lb0 = &Bt[ci0 * 8];
  ushort* lb1 = &Bt[(ci0 + 64) * 8];

  for (int k0 = 0; k0 < 25; ++k0) {
    __syncthreads();
    int kb = k0 * 32;  // ushort offset per row
    __builtin_amdgcn_global_load_lds(
        (const __attribute__((address_space(1))) unsigned int*)(ga0 + kb),
        (__attribute__((address_space(3))) unsigned int*)la0, 16, 0, 0);
    __builtin_amdgcn_global_load_lds(
        (const __attribute__((address_space(1))) unsigned int*)(ga1 + kb),
        (__attribute__((address_space(3))) unsigned int*)la1, 16, 0, 0);
    __builtin_amdgcn_global_load_lds(
        (const __attribute__((address_space(1))) unsigned int*)(gb0 + kb),
        (__attribute__((address_space(3))) unsigned int*)lb0, 16, 0, 0);
    __builtin_amdgcn_global_load_lds(
        (const __attribute__((address_space(1))) unsigned int*)(gb1 + kb),
        (__attribute__((address_space(3))) unsigned int*)lb1, 16, 0, 0);
    __syncthreads();
    bf16x8 af[4], bf[4];
    for (int i = 0; i < 4; ++i) {
      int m = wrow + i * 16 + ln;
      af[i] = *(const bf16x8*)&At[(m * 4 + (quad ^ (m & 3))) * 8];
    }
    for (int j = 0; j < 4; ++j) {
      int n = wcol + j * 16 + ln;
      bf[j] = *(const bf16x8*)&Bt[(n * 4 + (quad ^ (n & 3))) * 8];
    }
    for (int i = 0; i < 4; ++i)
      for (int j = 0; j < 4; ++j)
        acc[i][j] = __builtin_amdgcn_mfma_f32_16x16x32_bf16(af[i], bf[j], acc[i][j], 0, 0, 0);
  }

  // epilogue: d = sqrt(max(|a|^2+|b|^2-2ab, 1e-12))
  const float* rn = (mode ? bnorm : anorm) + c * 128;
  const float* cn = bnorm + c * 128;
  float cnv[4];
  for (int j = 0; j < 4; ++j) cnv[j] = cn[wcol + j * 16 + ln];
  float d[4][4][4];  // [i][j][reg]
  for (int i = 0; i < 4; ++i) {
    float rv[4];
    for (int r = 0; r < 4; ++r) rv[r] = rn[wrow + i * 16 + quad * 4 + r];
    for (int j = 0; j < 4; ++j)
      for (int r = 0; r < 4; ++r) {
        float d2 = rv[r] + cnv[j] - 2.f * acc[i][j][r];
        d[i][j][r] = sqrtf(fmaxf(d2, 1e-12f));
      }
  }

  if (mode) {
    float* ob = out_c + (size_t)c * (128 * 128);
    for (int i = 0; i < 4; ++i)
      for (int r = 0; r < 4; ++r) {
        int m = wrow + i * 16 + quad * 4 + r;
        for (int j = 0; j < 4; ++j) ob[m * 128 + wcol + j * 16 + ln] = d[i][j][r];
      }
  } else {
    int half = w & 1;
    for (int i = 0; i < 4; ++i)
      for (int r = 0; r < 4; ++r) {
        int m = wrow + i * 16 + quad * 4 + r;
        size_t ob = ((size_t)m * 256 + c) * 128 + wcol;
        for (int j = 0; j < 4; ++j) out_d[ob + j * 16 + ln] = d[i][j][r];
        float mn = fminf(fminf(d[i][0][r], d[i][1][r]), fminf(d[i][2][r], d[i][3][r]));
        for (int off = 1; off < 16; off <<= 1) mn = fminf(mn, __shfl_xor(mn, off, 64));
        if (ln == 0) smin[half][m] = mn;
      }
    __syncthreads();
    for (int i = 0; i < 4; ++i)
      for (int r = 0; r < 4; ++r) {
        int m = wrow + i * 16 + quad * 4 + r;
        float mn = fminf(smin[0][m], smin[1][m]);
        float s = 0.f;
        for (int j = 0; j < 4; ++j) {
          float e = __expf(-32.f * (d[i][j][r] - mn));
          d[i][j][r] = e;
          s += e;
        }
        for (int off = 1; off < 16; off <<= 1) s += __shfl_xor(s, off, 64);
        if (ln == 0) ssum[half][m] = s;
      }
    __syncthreads();
    for (int i = 0; i < 4; ++i)
      for (int r = 0; r < 4; ++r) {
        int m = wrow + i * 16 + quad * 4 + r;
        float inv = 1.f / (ssum[0][m] + ssum[1][m]);
        size_t ob = ((size_t)m * 256 + c) * 128 + wcol;
        for (int j = 0; j < 4; ++j) out_s[ob + j * 16 + ln] = d[i][j][r] * inv;
      }
  }
}

extern "C" void kernel_launch(void* const* d_in, const int* in_sizes, int n_in,
                              void* d_out, int out_size, void* d_ws, size_t ws_size,
                              hipStream_t stream) {
  const float* x   = (const float*)d_in[0];
  const float* lnw = (const float*)d_in[1];
  const float* lnb = (const float*)d_in[2];
  const float* cc  = (const float*)d_in[3];
  float* out   = (float*)d_out;
  float* out_d = out;             // x_distance        [8,16,256,128]
  float* out_s = out + 4194304;   // x_distance_assign [8,16,256,128]
  float* out_c = out + 8388608;   // cluster_dist      [256,128,128]

  ushort* xre_b = (ushort*)d_ws;            // 256*128*800 bf16 = 52.4 MB
  ushort* cc_b  = xre_b + 26214400;         // 52.4 MB
  float*  anorm = (float*)(cc_b + 26214400);  // 256*128 fp32
  float*  bnorm = anorm + 32768;

  hipMemsetAsync(anorm, 0, 32768 * sizeof(float), stream);
  ln_transpose_kernel<<<dim3(14, 128), 256, 0, stream>>>(x, lnw, lnb, xre_b, anorm);
  cc_convert_kernel<<<1024, 256, 0, stream>>>(cc, cc_b, bnorm);
  gemm_mfma_kernel<<<dim3(256, 2), 256, 0, stream>>>(xre_b, cc_b, anorm, bnorm,
                                                     out_d, out_s, out_c);
}

// Round 3
// 318.756 us; speedup vs baseline: 1.6701x; 1.0099x over previous
//
#include <hip/hip_runtime.h>
#include <hip/hip_bf16.h>
#include <math.h>

// Problem constants
#define C_DIM 256
#define BD    128   // B*D
#define HW    784   // H*W = K
#define CN    128
#define KPAD  800   // K padded to 25 tiles of 32 (pad = zeros)

typedef short bf16x8 __attribute__((ext_vector_type(8)));
typedef float f32x4 __attribute__((ext_vector_type(4)));

// fp32 -> bf16 RNE
__device__ inline ushort f2b(float f) {
  unsigned u = __float_as_uint(f);
  unsigned r = (u + 0x7FFFu + ((u >> 16) & 1u)) >> 16;
  return (ushort)r;
}

// ---------------------------------------------------------------------------
// K1: LayerNorm over C + transpose -> bf16 x_re [C][BD][KPAD] + row norms.
// grid (7, 128), block 256. Wave w owns rows w*28 .. w*28+27 end-to-end in
// registers (float4 load, shuffle-reduce LN, f2b), drops bf16 into a
// transposed LDS tile [256][114], then 224B-coalesced uint stores.
// ---------------------------------------------------------------------------
__global__ __launch_bounds__(256) void ln_transpose_kernel(
    const float* __restrict__ x, const float* __restrict__ lnw,
    const float* __restrict__ lnb, ushort* __restrict__ xre,
    float* __restrict__ anorm) {
  __shared__ ushort btile[256 * 114];   // [c][hw_local], 58.4 KB
  __shared__ float nbuf[4][256];
  const int t = threadIdx.x, bd = blockIdx.y, hw0 = blockIdx.x * 112;
  const int w = t >> 6, lane = t & 63;
  const int c0 = lane * 4;
  const float4 wv = *(const float4*)(lnw + c0);
  const float4 bvv = *(const float4*)(lnb + c0);
  float nrm[4] = {0.f, 0.f, 0.f, 0.f};
  const float* xb = x + ((size_t)bd * HW + hw0 + w * 28) * 256;
  for (int rr = 0; rr < 14; ++rr) {
    ushort yb[2][4];
    for (int q = 0; q < 2; ++q) {
      int r = rr * 2 + q;
      float4 v = *(const float4*)(xb + (size_t)r * 256 + c0);
      float s = v.x + v.y + v.z + v.w;
      for (int off = 32; off >= 1; off >>= 1) s += __shfl_xor(s, off, 64);
      float mu = s * (1.f / 256.f);
      float dx = v.x - mu, dy = v.y - mu, dz = v.z - mu, dw = v.w - mu;
      float s2 = dx * dx + dy * dy + dz * dz + dw * dw;
      for (int off = 32; off >= 1; off >>= 1) s2 += __shfl_xor(s2, off, 64);
      float sc = rsqrtf(s2 * (1.f / 256.f) + 1e-5f);
      float y0 = dx * sc * wv.x + bvv.x;
      float y1 = dy * sc * wv.y + bvv.y;
      float y2 = dz * sc * wv.z + bvv.z;
      float y3 = dw * sc * wv.w + bvv.w;
      nrm[0] = fmaf(y0, y0, nrm[0]);
      nrm[1] = fmaf(y1, y1, nrm[1]);
      nrm[2] = fmaf(y2, y2, nrm[2]);
      nrm[3] = fmaf(y3, y3, nrm[3]);
      yb[q][0] = f2b(y0); yb[q][1] = f2b(y1);
      yb[q][2] = f2b(y2); yb[q][3] = f2b(y3);
    }
    int hwl = w * 28 + rr * 2;
    for (int j = 0; j < 4; ++j)
      *(ushort2*)&btile[(c0 + j) * 114 + hwl] = make_ushort2(yb[0][j], yb[1][j]);
  }
  for (int j = 0; j < 4; ++j) nbuf[w][c0 + j] = nrm[j];
  __syncthreads();
  float tot = nbuf[0][t] + nbuf[1][t] + nbuf[2][t] + nbuf[3][t];
  atomicAdd(&anorm[t * 128 + bd], tot);  // anorm[c][bd]
  // write-out: wave w -> channels w*64..w*64+63, lanes cover 2 hw each (uint)
  const bool pad = (blockIdx.x == 6) && (lane >= 56);
  ushort* ob = xre + (size_t)(w * 64) * (BD * KPAD) + (size_t)bd * KPAD + hw0 + lane * 2;
  for (int i = 0; i < 64; ++i) {
    int c = w * 64 + i;
    uint val = 0;
    if (lane < 56) val = *(const uint*)&btile[c * 114 + lane * 2];
    if (lane < 56 || pad) *(uint*)ob = val;   // pad lanes write zeros at k=784..799
    ob += (size_t)BD * KPAD;
  }
}

// ---------------------------------------------------------------------------
// K2: cc fp32 -> bf16 [C][CN][KPAD] + fp32 row norms + zero K-pad
// grid 1024, block 256; block b: c=b>>2, rows (b&3)*32 + wave*8 .. +8
// ---------------------------------------------------------------------------
__global__ __launch_bounds__(256) void cc_convert_kernel(
    const float* __restrict__ cc, ushort* __restrict__ ccb,
    float* __restrict__ bnorm) {
  int b = blockIdx.x, c = b >> 2;
  int t = threadIdx.x, w = t >> 6, lane = t & 63;
  int r0 = (b & 3) * 32 + w * 8;
  for (int it = 0; it < 8; ++it) {
    int r = r0 + it;
    const float4* src = (const float4*)(cc + ((size_t)c * CN + r) * HW);
    ushort* dst = ccb + (size_t)c * (CN * KPAD) + (size_t)r * KPAD;
    float nrm = 0.f;
    for (int f = lane; f < 196; f += 64) {
      float4 v = src[f];
      nrm = fmaf(v.x, v.x, nrm); nrm = fmaf(v.y, v.y, nrm);
      nrm = fmaf(v.z, v.z, nrm); nrm = fmaf(v.w, v.w, nrm);
      ushort4 o; o.x = f2b(v.x); o.y = f2b(v.y); o.z = f2b(v.z); o.w = f2b(v.w);
      *(ushort4*)(dst + f * 4) = o;
    }
    for (int off = 32; off >= 1; off >>= 1) nrm += __shfl_xor(nrm, off, 64);
    if (lane == 0) bnorm[c * 128 + r] = nrm;
    if (lane < 4) *(ushort4*)(dst + 784 + lane * 4) = make_ushort4(0, 0, 0, 0);
  }
}

// ---------------------------------------------------------------------------
// K3: MFMA GEMM-dist. grid (256, 2): y=0 -> x_re vs cc (dist + softmax),
// y=1 -> cc vs cc (cluster_dist). 128x128 tile, BK=32, 16x16x32 bf16 MFMA.
// LDS tiles staged via global_load_lds (16B/lane) with XOR chunk swizzle:
// chunk(row, q) stored at ci = row*4 + (q ^ (row&3)).
// ---------------------------------------------------------------------------
__global__ __launch_bounds__(256, 2) void gemm_mfma_kernel(
    const ushort* __restrict__ xre, const ushort* __restrict__ ccb,
    const float* __restrict__ anorm, const float* __restrict__ bnorm,
    float* __restrict__ out_d, float* __restrict__ out_s,
    float* __restrict__ out_c) {
  __shared__ __align__(16) ushort At[512 * 8];  // 128 rows x 32 bf16
  __shared__ __align__(16) ushort Bt[512 * 8];
  __shared__ float smin[2][128];
  __shared__ float ssum[2][128];
  const int c = blockIdx.x, mode = blockIdx.y;
  const int t = threadIdx.x, w = t >> 6, lane = t & 63;
  const int quad = lane >> 4, ln = lane & 15;
  const int wrow = (w >> 1) * 64, wcol = (w & 1) * 64;
  const ushort* Ag = (mode ? ccb : xre) + (size_t)c * (128 * KPAD);
  const ushort* Bg = ccb + (size_t)c * (128 * KPAD);

  f32x4 acc[4][4];
  for (int i = 0; i < 4; ++i)
    for (int j = 0; j < 4; ++j) acc[i][j] = f32x4{0.f, 0.f, 0.f, 0.f};

  // staging addressing: instruction s covers chunks ci = 128w+64s+lane
  const int ci0 = 128 * w;
  const int row0 = (ci0 + lane) >> 2;
  const int row1 = (ci0 + 64 + lane) >> 2;
  const int q0 = (lane & 3) ^ (row0 & 3);
  const int q1 = (lane & 3) ^ (row1 & 3);
  const ushort* ga0 = Ag + (size_t)row0 * KPAD + q0 * 8;
  const ushort* ga1 = Ag + (size_t)row1 * KPAD + q1 * 8;
  const ushort* gb0 = Bg + (size_t)row0 * KPAD + q0 * 8;
  const ushort* gb1 = Bg + (size_t)row1 * KPAD + q1 * 8;
  ushort* la0 = &At[ci0 * 8];
  ushort* la1 = &At[(ci0 + 64) * 8];
  ushort* lb0 = &Bt[ci0 * 8];
  ushort* lb1 = &Bt[(ci0 + 64) * 8];

  for (int k0 = 0; k0 < 25; ++k0) {
    __syncthreads();
    int kb = k0 * 32;  // ushort offset per row
    __builtin_amdgcn_global_load_lds(
        (const __attribute__((address_space(1))) unsigned int*)(ga0 + kb),
        (__attribute__((address_space(3))) unsigned int*)la0, 16, 0, 0);
    __builtin_amdgcn_global_load_lds(
        (const __attribute__((address_space(1))) unsigned int*)(ga1 + kb),
        (__attribute__((address_space(3))) unsigned int*)la1, 16, 0, 0);
    __builtin_amdgcn_global_load_lds(
        (const __attribute__((address_space(1))) unsigned int*)(gb0 + kb),
        (__attribute__((address_space(3))) unsigned int*)lb0, 16, 0, 0);
    __builtin_amdgcn_global_load_lds(
        (const __attribute__((address_space(1))) unsigned int*)(gb1 + kb),
        (__attribute__((address_space(3))) unsigned int*)lb1, 16, 0, 0);
    __syncthreads();
    bf16x8 af[4], bf[4];
    for (int i = 0; i < 4; ++i) {
      int m = wrow + i * 16 + ln;
      af[i] = *(const bf16x8*)&At[(m * 4 + (quad ^ (m & 3))) * 8];
    }
    for (int j = 0; j < 4; ++j) {
      int n = wcol + j * 16 + ln;
      bf[j] = *(const bf16x8*)&Bt[(n * 4 + (quad ^ (n & 3))) * 8];
    }
    for (int i = 0; i < 4; ++i)
      for (int j = 0; j < 4; ++j)
        acc[i][j] = __builtin_amdgcn_mfma_f32_16x16x32_bf16(af[i], bf[j], acc[i][j], 0, 0, 0);
  }

  // epilogue: d = sqrt(max(|a|^2+|b|^2-2ab, 1e-12))
  const float* rn = (mode ? bnorm : anorm) + c * 128;
  const float* cn = bnorm + c * 128;
  float cnv[4];
  for (int j = 0; j < 4; ++j) cnv[j] = cn[wcol + j * 16 + ln];
  float d[4][4][4];  // [i][j][reg]
  for (int i = 0; i < 4; ++i) {
    float rv[4];
    for (int r = 0; r < 4; ++r) rv[r] = rn[wrow + i * 16 + quad * 4 + r];
    for (int j = 0; j < 4; ++j)
      for (int r = 0; r < 4; ++r) {
        float d2 = rv[r] + cnv[j] - 2.f * acc[i][j][r];
        d[i][j][r] = sqrtf(fmaxf(d2, 1e-12f));
      }
  }

  if (mode) {
    float* ob = out_c + (size_t)c * (128 * 128);
    for (int i = 0; i < 4; ++i)
      for (int r = 0; r < 4; ++r) {
        int m = wrow + i * 16 + quad * 4 + r;
        for (int j = 0; j < 4; ++j) ob[m * 128 + wcol + j * 16 + ln] = d[i][j][r];
      }
  } else {
    int half = w & 1;
    for (int i = 0; i < 4; ++i)
      for (int r = 0; r < 4; ++r) {
        int m = wrow + i * 16 + quad * 4 + r;
        size_t ob = ((size_t)m * 256 + c) * 128 + wcol;
        for (int j = 0; j < 4; ++j) out_d[ob + j * 16 + ln] = d[i][j][r];
        float mn = fminf(fminf(d[i][0][r], d[i][1][r]), fminf(d[i][2][r], d[i][3][r]));
        for (int off = 1; off < 16; off <<= 1) mn = fminf(mn, __shfl_xor(mn, off, 64));
        if (ln == 0) smin[half][m] = mn;
      }
    __syncthreads();
    for (int i = 0; i < 4; ++i)
      for (int r = 0; r < 4; ++r) {
        int m = wrow + i * 16 + quad * 4 + r;
        float mn = fminf(smin[0][m], smin[1][m]);
        float s = 0.f;
        for (int j = 0; j < 4; ++j) {
          float e = __expf(-32.f * (d[i][j][r] - mn));
          d[i][j][r] = e;
          s += e;
        }
        for (int off = 1; off < 16; off <<= 1) s += __shfl_xor(s, off, 64);
        if (ln == 0) ssum[half][m] = s;
      }
    __syncthreads();
    for (int i = 0; i < 4; ++i)
      for (int r = 0; r < 4; ++r) {
        int m = wrow + i * 16 + quad * 4 + r;
        float inv = 1.f / (ssum[0][m] + ssum[1][m]);
        size_t ob = ((size_t)m * 256 + c) * 128 + wcol;
        for (int j = 0; j < 4; ++j) out_s[ob + j * 16 + ln] = d[i][j][r] * inv;
      }
  }
}

extern "C" void kernel_launch(void* const* d_in, const int* in_sizes, int n_in,
                              void* d_out, int out_size, void* d_ws, size_t ws_size,
                              hipStream_t stream) {
  const float* x   = (const float*)d_in[0];
  const float* lnw = (const float*)d_in[1];
  const float* lnb = (const float*)d_in[2];
  const float* cc  = (const float*)d_in[3];
  float* out   = (float*)d_out;
  float* out_d = out;             // x_distance        [8,16,256,128]
  float* out_s = out + 4194304;   // x_distance_assign [8,16,256,128]
  float* out_c = out + 8388608;   // cluster_dist      [256,128,128]

  ushort* xre_b = (ushort*)d_ws;            // 256*128*800 bf16 = 52.4 MB
  ushort* cc_b  = xre_b + 26214400;         // 52.4 MB
  float*  anorm = (float*)(cc_b + 26214400);  // 256*128 fp32
  float*  bnorm = anorm + 32768;

  hipMemsetAsync(anorm, 0, 32768 * sizeof(float), stream);
  ln_transpose_kernel<<<dim3(7, 128), 256, 0, stream>>>(x, lnw, lnb, xre_b, anorm);
  cc_convert_kernel<<<1024, 256, 0, stream>>>(cc, cc_b, bnorm);
  gemm_mfma_kernel<<<dim3(256, 2), 256, 0, stream>>>(xre_b, cc_b, anorm, bnorm,
                                                     out_d, out_s, out_c);
}

// Round 4
// 309.919 us; speedup vs baseline: 1.7177x; 1.0285x over previous
//
#include <hip/hip_runtime.h>
#include <hip/hip_bf16.h>
#include <math.h>

// Problem constants
#define C_DIM 256
#define BD    128   // B*D
#define HW    784   // H*W = K
#define CN    128
#define KPAD  800   // K padded to 25 tiles of 32 (pad = zeros)

typedef short bf16x8 __attribute__((ext_vector_type(8)));
typedef float f32x4 __attribute__((ext_vector_type(4)));

// fp32 -> bf16 RNE
__device__ inline ushort f2b(float f) {
  unsigned u = __float_as_uint(f);
  unsigned r = (u + 0x7FFFu + ((u >> 16) & 1u)) >> 16;
  return (ushort)r;
}

// ---------------------------------------------------------------------------
// K1: LayerNorm over C + transpose -> bf16 x_re [C][BD][KPAD] + row norms.
// grid (13, 128), block 256. Quad-row design: each 16-lane quad owns one hw
// row; a wave LNs 4 rows per iteration in the same instructions (4-step
// shuffle reductions, 4-row ILP). Blocks 0..11: 64 rows; block 12: 16 rows
// + KPAD zero fill. LDS tile [c][66] -> 33.8 KB -> 4 blocks/CU.
// ---------------------------------------------------------------------------
__global__ __launch_bounds__(256) void ln_transpose_kernel(
    const float* __restrict__ x, const float* __restrict__ lnw,
    const float* __restrict__ lnb, ushort* __restrict__ xre,
    float* __restrict__ anorm) {
  __shared__ ushort btile[256 * 66];   // [c][hw_local], 33.8 KB
  __shared__ float nbuf[4][256];
  const int t = threadIdx.x, bd = blockIdx.y, bx = blockIdx.x;
  const int hw0 = bx * 64;
  const int w = t >> 6, lane = t & 63;
  const int q = lane >> 4, l = lane & 15;
  const bool last = (bx == 12);
  const int ngroups = last ? 1 : 4;       // row-groups per wave
  const int rpw = ngroups * 4;            // rows per wave
  float4 wv[4], bv[4];
  for (int s = 0; s < 4; ++s) {
    wv[s] = *(const float4*)(lnw + s * 64 + l * 4);
    bv[s] = *(const float4*)(lnb + s * 64 + l * 4);
  }
  float nrm[4][4];
  for (int s = 0; s < 4; ++s)
    for (int j = 0; j < 4; ++j) nrm[s][j] = 0.f;
  const float* xb = x + ((size_t)bd * HW + hw0) * 256 + l * 4;
  for (int g = 0; g < ngroups; ++g) {
    int r = w * rpw + g * 4 + q;          // block-local row
    float4 v[4];
    for (int s = 0; s < 4; ++s)
      v[s] = *(const float4*)(xb + (size_t)r * 256 + s * 64);
    float sum = 0.f;
    for (int s = 0; s < 4; ++s) sum += v[s].x + v[s].y + v[s].z + v[s].w;
    for (int off = 1; off <= 8; off <<= 1) sum += __shfl_xor(sum, off, 64);
    float mu = sum * (1.f / 256.f);
    float var = 0.f;
    for (int s = 0; s < 4; ++s) {
      float dx = v[s].x - mu, dy = v[s].y - mu, dz = v[s].z - mu, dw2 = v[s].w - mu;
      var += dx * dx + dy * dy + dz * dz + dw2 * dw2;
    }
    for (int off = 1; off <= 8; off <<= 1) var += __shfl_xor(var, off, 64);
    float sc = rsqrtf(var * (1.f / 256.f) + 1e-5f);
    for (int s = 0; s < 4; ++s) {
      float y0 = (v[s].x - mu) * sc * wv[s].x + bv[s].x;
      float y1 = (v[s].y - mu) * sc * wv[s].y + bv[s].y;
      float y2 = (v[s].z - mu) * sc * wv[s].z + bv[s].z;
      float y3 = (v[s].w - mu) * sc * wv[s].w + bv[s].w;
      nrm[s][0] = fmaf(y0, y0, nrm[s][0]);
      nrm[s][1] = fmaf(y1, y1, nrm[s][1]);
      nrm[s][2] = fmaf(y2, y2, nrm[s][2]);
      nrm[s][3] = fmaf(y3, y3, nrm[s][3]);
      int c = s * 64 + l * 4;
      btile[(c + 0) * 66 + r] = f2b(y0);
      btile[(c + 1) * 66 + r] = f2b(y1);
      btile[(c + 2) * 66 + r] = f2b(y2);
      btile[(c + 3) * 66 + r] = f2b(y3);
    }
  }
  // reduce norms over the 4 quads (same channel set), lanes q==0 publish
  for (int s = 0; s < 4; ++s)
    for (int j = 0; j < 4; ++j) {
      float v = nrm[s][j];
      v += __shfl_xor(v, 16, 64);
      v += __shfl_xor(v, 32, 64);
      nrm[s][j] = v;
    }
  if (q == 0)
    for (int s = 0; s < 4; ++s)
      for (int j = 0; j < 4; ++j) nbuf[w][s * 64 + l * 4 + j] = nrm[s][j];
  __syncthreads();
  float tot = nbuf[0][t] + nbuf[1][t] + nbuf[2][t] + nbuf[3][t];
  atomicAdd(&anorm[t * 128 + bd], tot);  // anorm[c][bd]
  // write-out
  if (!last) {
    for (int i = 0; i < 32; ++i) {
      int c = w * 64 + i * 2 + (lane >> 5);
      int hwp = (lane & 31) * 2;
      uint val = *(const uint*)&btile[c * 66 + hwp];
      *(uint*)(xre + (size_t)c * (BD * KPAD) + (size_t)bd * KPAD + hw0 + hwp) = val;
    }
  } else {
    for (int i = 0; i < 8; ++i) {
      int c = w * 64 + i * 8 + (lane >> 3);
      int hwp = (lane & 7) * 2;
      uint val = *(const uint*)&btile[c * 66 + hwp];
      ushort* gp = xre + (size_t)c * (BD * KPAD) + (size_t)bd * KPAD + 768;
      *(uint*)(gp + hwp) = val;
      *(uint*)(gp + 16 + hwp) = 0u;   // zero pad k = 784..799
    }
  }
}

// ---------------------------------------------------------------------------
// K2: cc fp32 -> bf16 [C][CN][KPAD] + fp32 row norms + zero K-pad
// grid 1024, block 256; block b: c=b>>2, rows (b&3)*32 + wave*8 .. +8
// ---------------------------------------------------------------------------
__global__ __launch_bounds__(256) void cc_convert_kernel(
    const float* __restrict__ cc, ushort* __restrict__ ccb,
    float* __restrict__ bnorm) {
  int b = blockIdx.x, c = b >> 2;
  int t = threadIdx.x, w = t >> 6, lane = t & 63;
  int r0 = (b & 3) * 32 + w * 8;
  for (int it = 0; it < 8; ++it) {
    int r = r0 + it;
    const float4* src = (const float4*)(cc + ((size_t)c * CN + r) * HW);
    ushort* dst = ccb + (size_t)c * (CN * KPAD) + (size_t)r * KPAD;
    float nrm = 0.f;
    for (int f = lane; f < 196; f += 64) {
      float4 v = src[f];
      nrm = fmaf(v.x, v.x, nrm); nrm = fmaf(v.y, v.y, nrm);
      nrm = fmaf(v.z, v.z, nrm); nrm = fmaf(v.w, v.w, nrm);
      ushort4 o; o.x = f2b(v.x); o.y = f2b(v.y); o.z = f2b(v.z); o.w = f2b(v.w);
      *(ushort4*)(dst + f * 4) = o;
    }
    for (int off = 32; off >= 1; off >>= 1) nrm += __shfl_xor(nrm, off, 64);
    if (lane == 0) bnorm[c * 128 + r] = nrm;
    if (lane < 4) *(ushort4*)(dst + 784 + lane * 4) = make_ushort4(0, 0, 0, 0);
  }
}

// ---------------------------------------------------------------------------
// K3: MFMA GEMM-dist. grid (256, 2): y=0 -> x_re vs cc (dist + softmax),
// y=1 -> cc vs cc (cluster_dist). 128x128 tile, BK=32, 16x16x32 bf16 MFMA.
// LDS tiles staged via global_load_lds (16B/lane) with XOR chunk swizzle:
// chunk(row, q) stored at ci = row*4 + (q ^ (row&3)).
// ---------------------------------------------------------------------------
__global__ __launch_bounds__(256, 2) void gemm_mfma_kernel(
    const ushort* __restrict__ xre, const ushort* __restrict__ ccb,
    const float* __restrict__ anorm, const float* __restrict__ bnorm,
    float* __restrict__ out_d, float* __restrict__ out_s,
    float* __restrict__ out_c) {
  __shared__ __align__(16) ushort At[512 * 8];  // 128 rows x 32 bf16
  __shared__ __align__(16) ushort Bt[512 * 8];
  __shared__ float smin[2][128];
  __shared__ float ssum[2][128];
  const int c = blockIdx.x, mode = blockIdx.y;
  const int t = threadIdx.x, w = t >> 6, lane = t & 63;
  const int quad = lane >> 4, ln = lane & 15;
  const int wrow = (w >> 1) * 64, wcol = (w & 1) * 64;
  const ushort* Ag = (mode ? ccb : xre) + (size_t)c * (128 * KPAD);
  const ushort* Bg = ccb + (size_t)c * (128 * KPAD);

  f32x4 acc[4][4];
  for (int i = 0; i < 4; ++i)
    for (int j = 0; j < 4; ++j) acc[i][j] = f32x4{0.f, 0.f, 0.f, 0.f};

  // staging addressing: instruction s covers chunks ci = 128w+64s+lane
  const int ci0 = 128 * w;
  const int row0 = (ci0 + lane) >> 2;
  const int row1 = (ci0 + 64 + lane) >> 2;
  const int q0 = (lane & 3) ^ (row0 & 3);
  const int q1 = (lane & 3) ^ (row1 & 3);
  const ushort* ga0 = Ag + (size_t)row0 * KPAD + q0 * 8;
  const ushort* ga1 = Ag + (size_t)row1 * KPAD + q1 * 8;
  const ushort* gb0 = Bg + (size_t)row0 * KPAD + q0 * 8;
  const ushort* gb1 = Bg + (size_t)row1 * KPAD + q1 * 8;
  ushort* la0 = &At[ci0 * 8];
  ushort* la1 = &At[(ci0 + 64) * 8];
  ushort* lb0 = &Bt[ci0 * 8];
  ushort* lb1 = &Bt[(ci0 + 64) * 8];

  for (int k0 = 0; k0 < 25; ++k0) {
    __syncthreads();
    int kb = k0 * 32;  // ushort offset per row
    __builtin_amdgcn_global_load_lds(
        (const __attribute__((address_space(1))) unsigned int*)(ga0 + kb),
        (__attribute__((address_space(3))) unsigned int*)la0, 16, 0, 0);
    __builtin_amdgcn_global_load_lds(
        (const __attribute__((address_space(1))) unsigned int*)(ga1 + kb),
        (__attribute__((address_space(3))) unsigned int*)la1, 16, 0, 0);
    __builtin_amdgcn_global_load_lds(
        (const __attribute__((address_space(1))) unsigned int*)(gb0 + kb),
        (__attribute__((address_space(3))) unsigned int*)lb0, 16, 0, 0);
    __builtin_amdgcn_global_load_lds(
        (const __attribute__((address_space(1))) unsigned int*)(gb1 + kb),
        (__attribute__((address_space(3))) unsigned int*)lb1, 16, 0, 0);
    __syncthreads();
    bf16x8 af[4], bf[4];
    for (int i = 0; i < 4; ++i) {
      int m = wrow + i * 16 + ln;
      af[i] = *(const bf16x8*)&At[(m * 4 + (quad ^ (m & 3))) * 8];
    }
    for (int j = 0; j < 4; ++j) {
      int n = wcol + j * 16 + ln;
      bf[j] = *(const bf16x8*)&Bt[(n * 4 + (quad ^ (n & 3))) * 8];
    }
    for (int i = 0; i < 4; ++i)
      for (int j = 0; j < 4; ++j)
        acc[i][j] = __builtin_amdgcn_mfma_f32_16x16x32_bf16(af[i], bf[j], acc[i][j], 0, 0, 0);
  }

  // epilogue: d = sqrt(max(|a|^2+|b|^2-2ab, 1e-12))
  const float* rn = (mode ? bnorm : anorm) + c * 128;
  const float* cn = bnorm + c * 128;
  float cnv[4];
  for (int j = 0; j < 4; ++j) cnv[j] = cn[wcol + j * 16 + ln];
  float d[4][4][4];  // [i][j][reg]
  for (int i = 0; i < 4; ++i) {
    float rv[4];
    for (int r = 0; r < 4; ++r) rv[r] = rn[wrow + i * 16 + quad * 4 + r];
    for (int j = 0; j < 4; ++j)
      for (int r = 0; r < 4; ++r) {
        float d2 = rv[r] + cnv[j] - 2.f * acc[i][j][r];
        d[i][j][r] = sqrtf(fmaxf(d2, 1e-12f));
      }
  }

  if (mode) {
    float* ob = out_c + (size_t)c * (128 * 128);
    for (int i = 0; i < 4; ++i)
      for (int r = 0; r < 4; ++r) {
        int m = wrow + i * 16 + quad * 4 + r;
        for (int j = 0; j < 4; ++j) ob[m * 128 + wcol + j * 16 + ln] = d[i][j][r];
      }
  } else {
    int half = w & 1;
    for (int i = 0; i < 4; ++i)
      for (int r = 0; r < 4; ++r) {
        int m = wrow + i * 16 + quad * 4 + r;
        size_t ob = ((size_t)m * 256 + c) * 128 + wcol;
        for (int j = 0; j < 4; ++j) out_d[ob + j * 16 + ln] = d[i][j][r];
        float mn = fminf(fminf(d[i][0][r], d[i][1][r]), fminf(d[i][2][r], d[i][3][r]));
        for (int off = 1; off < 16; off <<= 1) mn = fminf(mn, __shfl_xor(mn, off, 64));
        if (ln == 0) smin[half][m] = mn;
      }
    __syncthreads();
    for (int i = 0; i < 4; ++i)
      for (int r = 0; r < 4; ++r) {
        int m = wrow + i * 16 + quad * 4 + r;
        float mn = fminf(smin[0][m], smin[1][m]);
        float s = 0.f;
        for (int j = 0; j < 4; ++j) {
          float e = __expf(-32.f * (d[i][j][r] - mn));
          d[i][j][r] = e;
          s += e;
        }
        for (int off = 1; off < 16; off <<= 1) s += __shfl_xor(s, off, 64);
        if (ln == 0) ssum[half][m] = s;
      }
    __syncthreads();
    for (int i = 0; i < 4; ++i)
      for (int r = 0; r < 4; ++r) {
        int m = wrow + i * 16 + quad * 4 + r;
        float inv = 1.f / (ssum[0][m] + ssum[1][m]);
        size_t ob = ((size_t)m * 256 + c) * 128 + wcol;
        for (int j = 0; j < 4; ++j) out_s[ob + j * 16 + ln] = d[i][j][r] * inv;
      }
  }
}

extern "C" void kernel_launch(void* const* d_in, const int* in_sizes, int n_in,
                              void* d_out, int out_size, void* d_ws, size_t ws_size,
                              hipStream_t stream) {
  const float* x   = (const float*)d_in[0];
  const float* lnw = (const float*)d_in[1];
  const float* lnb = (const float*)d_in[2];
  const float* cc  = (const float*)d_in[3];
  float* out   = (float*)d_out;
  float* out_d = out;             // x_distance        [8,16,256,128]
  float* out_s = out + 4194304;   // x_distance_assign [8,16,256,128]
  float* out_c = out + 8388608;   // cluster_dist      [256,128,128]

  ushort* xre_b = (ushort*)d_ws;            // 256*128*800 bf16 = 52.4 MB
  ushort* cc_b  = xre_b + 26214400;         // 52.4 MB
  float*  anorm = (float*)(cc_b + 26214400);  // 256*128 fp32
  float*  bnorm = anorm + 32768;

  hipMemsetAsync(anorm, 0, 32768 * sizeof(float), stream);
  ln_transpose_kernel<<<dim3(13, 128), 256, 0, stream>>>(x, lnw, lnb, xre_b, anorm);
  cc_convert_kernel<<<1024, 256, 0, stream>>>(cc, cc_b, bnorm);
  gemm_mfma_kernel<<<dim3(256, 2), 256, 0, stream>>>(xre_b, cc_b, anorm, bnorm,
                                                     out_d, out_s, out_c);
}